// Round 12
// baseline (75.931 us; speedup 1.0000x reference)
//
#include <hip/hip_runtime.h>
#include <hip/hip_bf16.h>

#define TSEQ 256
#define NBATCH 2
#define NAG 8
#define NH 8
#define HD 64
#define EE 512
#define WHALF 16
#define WW 33
#define WN 264   // WW*NAG

typedef __attribute__((ext_vector_type(8))) short short8;
typedef __attribute__((ext_vector_type(4))) short short4v;
typedef __attribute__((ext_vector_type(4))) float f32x4;
typedef _Float16 f16x8 __attribute__((ext_vector_type(8)));

static __device__ __forceinline__ unsigned short f2bf(float f) {
    unsigned int u = __float_as_uint(f);
    unsigned int r = (u + 0x7FFFu + ((u >> 16) & 1u)) >> 16;
    return (unsigned short)r;
}
static __device__ __forceinline__ unsigned short f2h(float f) {
    _Float16 h = (_Float16)f;
    return __builtin_bit_cast(unsigned short, h);
}
static __device__ __forceinline__ float h2f(unsigned short u) {
    return (float)__builtin_bit_cast(_Float16, u);
}
static __device__ __forceinline__ f16x8 as_f16x8(short8 s) {
    return __builtin_bit_cast(f16x8, s);
}

// ---------------- fused QKV projection GEMM (bf16 MFMA) -----------------
__global__ __launch_bounds__(256)
void proj_mfma_kernel(const float* __restrict__ xq, const float* __restrict__ xk,
                      const float* __restrict__ xv,
                      const float* __restrict__ Wq, const float* __restrict__ Wk,
                      const float* __restrict__ Wv,
                      const float* __restrict__ bq, const float* __restrict__ bk,
                      const float* __restrict__ bv,
                      unsigned short* __restrict__ oq, unsigned short* __restrict__ ok,
                      unsigned short* __restrict__ vt)
{
    __shared__ char As[128 * 128];   // 128 rows x 64 bf16 (swizzled)
    __shared__ char Bs[128 * 128];

    const float* x; const float* W; const float* bias; float scale;
    const int z = blockIdx.z;
    if (z == 0)      { x = xq; W = Wq; bias = bq; scale = 0.125f; }
    else if (z == 1) { x = xk; W = Wk; bias = bk; scale = 1.0f; }
    else             { x = xv; W = Wv; bias = bv; scale = 1.0f; }

    const int tid  = threadIdx.x;
    const int lane = tid & 63;
    const int wid  = tid >> 6;
    const int i0 = blockIdx.x * 128;
    const int f0 = blockIdx.y * 128;
    const int wr = wid >> 1, wc = wid & 1;

    f32x4 acc[4][4];
    #pragma unroll
    for (int m = 0; m < 4; ++m)
        #pragma unroll
        for (int n = 0; n < 4; ++n)
            acc[m][n] = (f32x4){0.f, 0.f, 0.f, 0.f};

    for (int k0 = 0; k0 < EE; k0 += 64) {
        #pragma unroll
        for (int it = 0; it < 8; ++it) {
            const int tt  = tid + it * 256;        // 0..2047
            const int row = tt >> 4, f4 = tt & 15;
            float4 v4 = *reinterpret_cast<const float4*>(x + (size_t)(i0 + row) * EE + k0 + f4 * 4);
            short4v s;
            s[0] = (short)f2bf(v4.x); s[1] = (short)f2bf(v4.y);
            s[2] = (short)f2bf(v4.z); s[3] = (short)f2bf(v4.w);
            *(short4v*)(As + row * 128 + ((f4 * 8) ^ ((row & 7) << 4))) = s;
        }
        #pragma unroll
        for (int it = 0; it < 8; ++it) {
            const int tt  = tid + it * 256;
            const int row = tt >> 4, f4 = tt & 15;
            float4 v4 = *reinterpret_cast<const float4*>(W + (size_t)(f0 + row) * EE + k0 + f4 * 4);
            short4v s;
            s[0] = (short)f2bf(v4.x); s[1] = (short)f2bf(v4.y);
            s[2] = (short)f2bf(v4.z); s[3] = (short)f2bf(v4.w);
            *(short4v*)(Bs + row * 128 + ((f4 * 8) ^ ((row & 7) << 4))) = s;
        }
        __syncthreads();

        #pragma unroll
        for (int ks = 0; ks < 2; ++ks) {
            short8 a[4], b[4];
            #pragma unroll
            for (int m = 0; m < 4; ++m) {
                const int row = wr * 64 + m * 16 + (lane & 15);
                a[m] = *(short8*)(As + row * 128 +
                                  ((ks * 64 + (lane >> 4) * 16) ^ ((row & 7) << 4)));
            }
            #pragma unroll
            for (int n = 0; n < 4; ++n) {
                const int row = wc * 64 + n * 16 + (lane & 15);
                b[n] = *(short8*)(Bs + row * 128 +
                                  ((ks * 64 + (lane >> 4) * 16) ^ ((row & 7) << 4)));
            }
            #pragma unroll
            for (int m = 0; m < 4; ++m)
                #pragma unroll
                for (int n = 0; n < 4; ++n)
                    acc[m][n] = __builtin_amdgcn_mfma_f32_16x16x32_bf16(a[m], b[n], acc[m][n], 0, 0, 0);
        }
        __syncthreads();
    }

    if (z < 2) {
        unsigned short* o = (z == 0) ? oq : ok;
        #pragma unroll
        for (int n = 0; n < 4; ++n) {
            const int col = f0 + wc * 64 + n * 16 + (lane & 15);
            const float bb = bias[col];
            #pragma unroll
            for (int m = 0; m < 4; ++m)
                #pragma unroll
                for (int rg = 0; rg < 4; ++rg) {
                    const int row = i0 + wr * 64 + m * 16 + (lane >> 4) * 4 + rg;
                    o[(size_t)row * EE + col] = f2bf((acc[m][n][rg] + bb) * scale);
                }
        }
    } else {
        // transposed f16 store: vt[((b*8+h)*64+d)*2048 + (t*8+m)]
        #pragma unroll
        for (int n = 0; n < 4; ++n) {
            const int col = f0 + wc * 64 + n * 16 + (lane & 15);
            const int h = col >> 6, d = col & 63;
            const float bb = bias[col];
            #pragma unroll
            for (int m = 0; m < 4; ++m) {
                const int ibase = i0 + wr * 64 + m * 16 + (lane >> 4) * 4;
                const int bb_ = ibase >> 11;          // batch
                const int key = ibase & 2047;
                ushort4 s4;
                s4.x = f2h(acc[m][n][0] + bb);
                s4.y = f2h(acc[m][n][1] + bb);
                s4.z = f2h(acc[m][n][2] + bb);
                s4.w = f2h(acc[m][n][3] + bb);
                *(ushort4*)(vt + ((size_t)(bb_ * 8 + h) * 64 + d) * 2048 + key) = s4;
            }
        }
    }
}

// ---------------- attn phase 1: QK^T + softmax + attn write + P dump ---------
// Block = (b, t). 512 threads = 8 waves; wave w owns head h = w.
#define RSW  296                        // u16 per P row
#define HS   2376                       // u16 per head buffer
#define KM_OFF_B  (8 * HS * 2)          // 38016
#define INV_OFF_B (KM_OFF_B + 288)      // 38304
#define SMEM2_BYTES (INV_OFF_B + 256 + 32)

__global__ __launch_bounds__(512, 6)
void attn_phase1_kernel(const unsigned short* __restrict__ qb,
                        const unsigned short* __restrict__ kb,
                        const unsigned char* __restrict__ kpm,
                        float* __restrict__ attn,
                        unsigned short* __restrict__ pw,   // [b,t,64 rows,288] f16
                        float* __restrict__ invw)          // [b,t,64]
{
    extern __shared__ char smem[];
    unsigned short* P16 = (unsigned short*)smem;
    char*  km   = smem + KM_OFF_B;
    float* invs = (float*)(smem + INV_OFF_B);

    const int bid = blockIdx.x;
    const int lin = (bid & 7) * 64 + (bid >> 3);   // XCD swizzle
    const int b   = lin >> 8;
    const int t   = lin & 255;
    const int j0  = t - WHALF;
    const int tid = threadIdx.x;
    const int lane = tid & 63;
    const int h    = tid >> 6;             // wave id == head

    if (tid < WN) {
        const int j = j0 + (tid >> 3), m = tid & 7;
        km[tid] = (j >= 0 && j < TSEQ && kpm[(b * TSEQ + j) * NAG + m] == 0) ? 1 : 0;
    }
    // zero P cols [272,296) for all 64 rows (dump/PV read up to col 287)
    for (int i = tid; i < 768; i += 512) {
        const int row = i / 12, cp = i - row * 12;
        *(unsigned int*)(smem + ((row >> 3) * HS + (row & 7) * RSW + 272 + cp * 2) * 2) = 0u;
    }

    // ---- QK^T per wave: D[8 real rows x 272 cols], depth-5 ring prefetch ----
    {
        const int n = lane & 7;
        const unsigned short* qbase = qb + ((size_t)(b * TSEQ + t) * NAG + n) * EE + h * HD;
        short8 aq0 = *(const short8*)(qbase + (lane >> 4) * 8);
        short8 aq1 = *(const short8*)(qbase + 32 + (lane >> 4) * 8);
        unsigned short* Ph = P16 + h * HS;
        const int r0 = (lane >> 4) * 4;
        const int cl = lane & 15;

        auto kaddr = [&](int f) -> const unsigned short* {
            const int c = f * 16 + cl;
            int j = j0 + (c >> 3);
            j = (j < 0) ? 0 : ((j > TSEQ - 1) ? TSEQ - 1 : j);
            return kb + ((size_t)(b * TSEQ + j) * NAG + (c & 7)) * EE + h * HD + (lane >> 4) * 8;
        };

        short8 ka[5], kb2[5];
        #pragma unroll
        for (int f = 0; f < 5; ++f) {
            const unsigned short* p = kaddr(f);
            ka[f]  = *(const short8*)p;
            kb2[f] = *(const short8*)(p + 32);
        }
        #pragma unroll
        for (int f = 0; f < 17; ++f) {
            f32x4 a = (f32x4){0.f, 0.f, 0.f, 0.f};
            a = __builtin_amdgcn_mfma_f32_16x16x32_bf16(aq0, ka[f % 5],  a, 0, 0, 0);
            a = __builtin_amdgcn_mfma_f32_16x16x32_bf16(aq1, kb2[f % 5], a, 0, 0, 0);
            if (f + 5 < 17) {
                const unsigned short* p = kaddr(f + 5);
                ka[f % 5]  = *(const short8*)p;
                kb2[f % 5] = *(const short8*)(p + 32);
            }
            if (r0 < 8) {
                #pragma unroll
                for (int rg = 0; rg < 4; ++rg)
                    Ph[(r0 + rg) * RSW + f * 16 + cl] = f2h(a[rg]);
            }
        }
    }
    __syncthreads();

    // ---- softmax per wave: 8 lanes/row; in-place f16 logits -> unnorm probs ----
    {
        const int r = lane & 7, sub = lane >> 3;
        unsigned short* prow = P16 + h * HS + r * RSW;
        float mx = -INFINITY;
        #pragma unroll
        for (int i = 0; i < 33; ++i) {
            const int c = sub + 8 * i;
            if (km[c]) mx = fmaxf(mx, h2f(prow[c]));
        }
        mx = fmaxf(mx, __shfl_xor(mx, 8));
        mx = fmaxf(mx, __shfl_xor(mx, 16));
        mx = fmaxf(mx, __shfl_xor(mx, 32));
        float sum = 0.f;
        #pragma unroll
        for (int i = 0; i < 34; ++i) {
            const int c = sub + 8 * i;                 // covers [0,272)
            float p = 0.f;
            if (c < WN && km[c]) p = __expf(h2f(prow[c]) - mx);
            prow[c] = f2h(p);
            sum += p;
        }
        sum += __shfl_xor(sum, 8);
        sum += __shfl_xor(sum, 16);
        sum += __shfl_xor(sum, 32);
        if (sub == 0) invs[h * 8 + r] = 1.f / sum;
    }
    __syncthreads();

    // ---- inv dump ----
    if (tid < 64) invw[(size_t)(b * TSEQ + t) * 64 + tid] = invs[tid];

    // ---- cooperative coalesced attn write: 4224 float4 contiguous ----
    {
        float* abase = attn + (size_t)(b * TSEQ + t) * (NAG * WN * NH);
        #pragma unroll 3
        for (int q4 = tid; q4 < 4224; q4 += 512) {
            const int hh = q4 & 1;
            const int rw = q4 >> 1;                    // n*264 + wm
            const int n  = rw / WN;
            const int wm = rw - n * WN;
            const int h0 = hh * 4;
            const unsigned short* pp = P16 + h0 * HS + n * RSW + wm;
            float4 v;
            v.x = h2f(pp[0])      * invs[(h0 + 0) * 8 + n];
            v.y = h2f(pp[HS])     * invs[(h0 + 1) * 8 + n];
            v.z = h2f(pp[2 * HS]) * invs[(h0 + 2) * 8 + n];
            v.w = h2f(pp[3 * HS]) * invs[(h0 + 3) * 8 + n];
            *(float4*)(abase + (size_t)q4 * 4) = v;
        }
    }

    // ---- compact P dump: 64 rows x 288 u16, 16B chunks, coalesced ----
    {
        unsigned short* pbase = pw + (size_t)(b * TSEQ + t) * 64 * 288;
        #pragma unroll 3
        for (int idx = tid; idx < 2304; idx += 512) {
            const int row = idx / 36;                  // h*8 + n
            const int c16 = idx - row * 36;            // 0..35
            short8 v = *(short8*)(P16 + (row >> 3) * HS + (row & 7) * RSW + c16 * 8);
            *(short8*)(pbase + (size_t)row * 288 + c16 * 8) = v;
        }
    }
}

// ---------------- attn phase 2: PV (no LDS, no barriers) --------------------
// Block = (b, t). 512 threads = 8 waves; wave w owns head h = w.
__global__ __launch_bounds__(512, 4)
void attn_pv_kernel(const unsigned short* __restrict__ pw,
                    const float* __restrict__ invw,
                    const unsigned short* __restrict__ vt,
                    float* __restrict__ out)
{
    const int bid = blockIdx.x;
    const int lin = (bid & 7) * 64 + (bid >> 3);   // same XCD swizzle as phase 1
    const int b   = lin >> 8;
    const int t   = lin & 255;
    const int key0 = (t - WHALF) * 8;
    const int tid = threadIdx.x;
    const int lane = tid & 63;
    const int h    = tid >> 6;

    const unsigned short* pbase = pw + ((size_t)(b * TSEQ + t) * 64 + h * 8) * 288;
    const unsigned short* arow  = pbase + (lane & 7) * 288;
    const unsigned short* vth   = vt + ((size_t)(b * 8 + h) * 64) * 2048;

    auto vaddr = [&](int ms, int df) -> const short8* {
        int kc = key0 + ms * 32 + (lane >> 4) * 8;
        kc = (kc < 0) ? 0 : ((kc > 2040) ? 2040 : kc);
        const int d = df * 16 + (lane & 15);
        return (const short8*)(vth + (size_t)d * 2048 + kc);
    };

    short8 vf[2][4];
    #pragma unroll
    for (int df = 0; df < 4; ++df) vf[0][df] = *vaddr(0, df);
    #pragma unroll
    for (int df = 0; df < 4; ++df) vf[1][df] = *vaddr(1, df);

    f32x4 acc[4];
    #pragma unroll
    for (int df = 0; df < 4; ++df) acc[df] = (f32x4){0.f, 0.f, 0.f, 0.f};

    #pragma unroll
    for (int ms = 0; ms < 9; ++ms) {
        short8 afr = *(const short8*)(arow + ms * 32 + (lane >> 4) * 8);
        #pragma unroll
        for (int df = 0; df < 4; ++df)
            acc[df] = __builtin_amdgcn_mfma_f32_16x16x32_f16(
                as_f16x8(afr), as_f16x8(vf[ms & 1][df]), acc[df], 0, 0, 0);
        if (ms + 2 < 9) {
            #pragma unroll
            for (int df = 0; df < 4; ++df) vf[ms & 1][df] = *vaddr(ms + 2, df);
        }
    }
    const int r0 = (lane >> 4) * 4;
    if (r0 < 8) {
        const float* ivp = invw + (size_t)(b * TSEQ + t) * 64 + h * 8;
        float iv[4];
        #pragma unroll
        for (int rg = 0; rg < 4; ++rg) iv[rg] = ivp[r0 + rg];
        #pragma unroll
        for (int df = 0; df < 4; ++df) {
            const int d = df * 16 + (lane & 15);
            #pragma unroll
            for (int rg = 0; rg < 4; ++rg) {
                const int n = r0 + rg;
                out[((size_t)(b * TSEQ + t) * NAG + n) * EE + h * HD + d] = acc[df][rg] * iv[rg];
            }
        }
    }
}

extern "C" void kernel_launch(void* const* d_in, const int* in_sizes, int n_in,
                              void* d_out, int out_size, void* d_ws, size_t ws_size,
                              hipStream_t stream) {
    const float* query = (const float*)d_in[0];
    const float* key   = (const float*)d_in[1];
    const float* value = (const float*)d_in[2];
    const unsigned char* kpm = (const unsigned char*)d_in[3];
    const float* Wq = (const float*)d_in[4];
    const float* bq = (const float*)d_in[5];
    const float* Wk = (const float*)d_in[6];
    const float* bk = (const float*)d_in[7];
    const float* Wv = (const float*)d_in[8];
    const float* bv = (const float*)d_in[9];

    float* out  = (float*)d_out;
    float* attn = out + (size_t)NBATCH * TSEQ * NAG * EE;

    unsigned short* qbf = (unsigned short*)d_ws;               // 4 MB bf16
    unsigned short* kbf = qbf + (size_t)4096 * EE;             // 4 MB bf16
    unsigned short* vtb = kbf + (size_t)4096 * EE;             // 4 MB f16 transposed V
    unsigned short* pw  = vtb + (size_t)4096 * EE;             // 18.9 MB compact f16 P
    float*          invw = (float*)(pw + (size_t)NBATCH * TSEQ * 64 * 288);  // 128 KB

    dim3 gp(32, 4, 3);
    proj_mfma_kernel<<<gp, 256, 0, stream>>>(query, key, value,
                                             Wq, Wk, Wv, bq, bk, bv,
                                             qbf, kbf, vtb);

    (void)hipFuncSetAttribute((const void*)attn_phase1_kernel,
                              hipFuncAttributeMaxDynamicSharedMemorySize, SMEM2_BYTES);
    attn_phase1_kernel<<<512, 512, SMEM2_BYTES, stream>>>(qbf, kbf, kpm, attn, pw, invw);
    attn_pv_kernel<<<512, 512, 0, stream>>>(pw, invw, vtb, out);
}

// Round 13
// 45.431 us; speedup vs baseline: 1.6714x; 1.6714x over previous
//
#include <hip/hip_runtime.h>
#include <hip/hip_bf16.h>

#define TSEQ 256
#define NBATCH 2
#define NAG 8
#define NH 8
#define HD 64
#define EE 512
#define WHALF 16
#define WW 33
#define WN 264   // WW*NAG

typedef __attribute__((ext_vector_type(8))) short short8;
typedef __attribute__((ext_vector_type(4))) short short4v;
typedef __attribute__((ext_vector_type(4))) float f32x4;
typedef _Float16 f16x8 __attribute__((ext_vector_type(8)));

static __device__ __forceinline__ unsigned short f2bf(float f) {
    unsigned int u = __float_as_uint(f);
    unsigned int r = (u + 0x7FFFu + ((u >> 16) & 1u)) >> 16;
    return (unsigned short)r;
}
static __device__ __forceinline__ unsigned short f2h(float f) {
    _Float16 h = (_Float16)f;
    return __builtin_bit_cast(unsigned short, h);
}
static __device__ __forceinline__ float h2f(unsigned short u) {
    return (float)__builtin_bit_cast(_Float16, u);
}
static __device__ __forceinline__ f16x8 as_f16x8(short8 s) {
    return __builtin_bit_cast(f16x8, s);
}

// ---------------- fused QKV projection GEMM (bf16 MFMA) -----------------
// BM=128, BN=128, BK=64, 4 waves. z picks {q,k,v}.
// z==0: q normal bf16 [b,t,n,E].
// z==1: k scattered into MFMA-fragment order (bf16):
//   kswz[(b*8+h)*131072 + (c>>4)*1024 + (d>>5)*512 + ((d&31)>>3)*128 + (c&15)*8 + (d&7)]
//   (c = global key j*8+m in [0,2048), d in [0,64))
// z==2: v scattered into PV B-fragment order (f16):
//   vswz[(b*8+h)*131072 + (c>>5)*2048 + (d>>4)*512 + ((c>>3)&3)*128 + (d&15)*8 + (c&7)]
__global__ __launch_bounds__(256)
void proj_mfma_kernel(const float* __restrict__ xq, const float* __restrict__ xk,
                      const float* __restrict__ xv,
                      const float* __restrict__ Wq, const float* __restrict__ Wk,
                      const float* __restrict__ Wv,
                      const float* __restrict__ bq, const float* __restrict__ bk,
                      const float* __restrict__ bv,
                      unsigned short* __restrict__ oq,
                      unsigned short* __restrict__ kswz,
                      unsigned short* __restrict__ vswz)
{
    __shared__ char As[128 * 128];
    __shared__ char Bs[128 * 128];

    const float* x; const float* W; const float* bias; float scale;
    const int z = blockIdx.z;
    if (z == 0)      { x = xq; W = Wq; bias = bq; scale = 0.125f; }
    else if (z == 1) { x = xk; W = Wk; bias = bk; scale = 1.0f; }
    else             { x = xv; W = Wv; bias = bv; scale = 1.0f; }

    const int tid  = threadIdx.x;
    const int lane = tid & 63;
    const int wid  = tid >> 6;
    const int i0 = blockIdx.x * 128;
    const int f0 = blockIdx.y * 128;
    const int wr = wid >> 1, wc = wid & 1;

    f32x4 acc[4][4];
    #pragma unroll
    for (int m = 0; m < 4; ++m)
        #pragma unroll
        for (int n = 0; n < 4; ++n)
            acc[m][n] = (f32x4){0.f, 0.f, 0.f, 0.f};

    for (int k0 = 0; k0 < EE; k0 += 64) {
        #pragma unroll
        for (int it = 0; it < 8; ++it) {
            const int tt  = tid + it * 256;
            const int row = tt >> 4, f4 = tt & 15;
            float4 v4 = *reinterpret_cast<const float4*>(x + (size_t)(i0 + row) * EE + k0 + f4 * 4);
            short4v s;
            s[0] = (short)f2bf(v4.x); s[1] = (short)f2bf(v4.y);
            s[2] = (short)f2bf(v4.z); s[3] = (short)f2bf(v4.w);
            *(short4v*)(As + row * 128 + ((f4 * 8) ^ ((row & 7) << 4))) = s;
        }
        #pragma unroll
        for (int it = 0; it < 8; ++it) {
            const int tt  = tid + it * 256;
            const int row = tt >> 4, f4 = tt & 15;
            float4 v4 = *reinterpret_cast<const float4*>(W + (size_t)(f0 + row) * EE + k0 + f4 * 4);
            short4v s;
            s[0] = (short)f2bf(v4.x); s[1] = (short)f2bf(v4.y);
            s[2] = (short)f2bf(v4.z); s[3] = (short)f2bf(v4.w);
            *(short4v*)(Bs + row * 128 + ((f4 * 8) ^ ((row & 7) << 4))) = s;
        }
        __syncthreads();

        #pragma unroll
        for (int ks = 0; ks < 2; ++ks) {
            short8 a[4], b[4];
            #pragma unroll
            for (int m = 0; m < 4; ++m) {
                const int row = wr * 64 + m * 16 + (lane & 15);
                a[m] = *(short8*)(As + row * 128 +
                                  ((ks * 64 + (lane >> 4) * 16) ^ ((row & 7) << 4)));
            }
            #pragma unroll
            for (int n = 0; n < 4; ++n) {
                const int row = wc * 64 + n * 16 + (lane & 15);
                b[n] = *(short8*)(Bs + row * 128 +
                                  ((ks * 64 + (lane >> 4) * 16) ^ ((row & 7) << 4)));
            }
            #pragma unroll
            for (int m = 0; m < 4; ++m)
                #pragma unroll
                for (int n = 0; n < 4; ++n)
                    acc[m][n] = __builtin_amdgcn_mfma_f32_16x16x32_bf16(a[m], b[n], acc[m][n], 0, 0, 0);
        }
        __syncthreads();
    }

    if (z == 0) {
        #pragma unroll
        for (int n = 0; n < 4; ++n) {
            const int col = f0 + wc * 64 + n * 16 + (lane & 15);
            const float bb = bias[col];
            #pragma unroll
            for (int m = 0; m < 4; ++m)
                #pragma unroll
                for (int rg = 0; rg < 4; ++rg) {
                    const int row = i0 + wr * 64 + m * 16 + (lane >> 4) * 4 + rg;
                    oq[(size_t)row * EE + col] = f2bf((acc[m][n][rg] + bb) * scale);
                }
        }
    } else if (z == 1) {
        #pragma unroll
        for (int n = 0; n < 4; ++n) {
            const int col = f0 + wc * 64 + n * 16 + (lane & 15);
            const int h = col >> 6, d = col & 63;
            const float bb = bias[col];
            const size_t dpart = (size_t)((d >> 5) * 512 + ((d & 31) >> 3) * 128 + (d & 7));
            #pragma unroll
            for (int m = 0; m < 4; ++m) {
                #pragma unroll
                for (int rg = 0; rg < 4; ++rg) {
                    const int i = i0 + wr * 64 + m * 16 + (lane >> 4) * 4 + rg;
                    const int b_ = i >> 11, c = i & 2047;
                    kswz[(size_t)(b_ * 8 + h) * 131072 + (size_t)(c >> 4) * 1024 +
                         (size_t)(c & 15) * 8 + dpart] = f2bf(acc[m][n][rg] + bb);
                }
            }
        }
    } else {
        #pragma unroll
        for (int n = 0; n < 4; ++n) {
            const int col = f0 + wc * 64 + n * 16 + (lane & 15);
            const int h = col >> 6, d = col & 63;
            const float bb = bias[col];
            const size_t dpart = (size_t)((d >> 4) * 512 + (d & 15) * 8);
            #pragma unroll
            for (int m = 0; m < 4; ++m) {
                #pragma unroll
                for (int rg = 0; rg < 4; ++rg) {
                    const int i = i0 + wr * 64 + m * 16 + (lane >> 4) * 4 + rg;
                    const int b_ = i >> 11, c = i & 2047;
                    vswz[(size_t)(b_ * 8 + h) * 131072 + (size_t)(c >> 5) * 2048 +
                         (size_t)((c >> 3) & 3) * 128 + (size_t)(c & 7) + dpart] = f2h(acc[m][n][rg] + bb);
                }
            }
        }
    }
}

// ---------------- fused all-heads windowed attention ------------------------
// Block = (b, t). 512 threads = 8 waves; wave w owns head h = w.
// K/V read via lane-linear fragment loads (1 KB contiguous per instruction).
// Window aligned: jstart = (t-16)&~3, 36 j's = 288 keys; off8 shifts attn cols.
#define RSW  296                        // u16 per P row
#define HS   2376                       // u16 per head buffer (8*296+8)
#define KM_OFF_B  (8 * HS * 2)          // 38016
#define INV_OFF_B (KM_OFF_B + 288)      // 38304
#define SMEM2_BYTES (INV_OFF_B + 256 + 32)

__global__ __launch_bounds__(512, 6)
void attn_fused_kernel(const unsigned short* __restrict__ qb,
                       const unsigned short* __restrict__ kswz,
                       const unsigned short* __restrict__ vswz,
                       const unsigned char* __restrict__ kpm,
                       float* __restrict__ out,
                       float* __restrict__ attn)
{
    extern __shared__ char smem[];
    unsigned short* P16 = (unsigned short*)smem;
    char*  km   = smem + KM_OFF_B;
    float* invs = (float*)(smem + INV_OFF_B);

    const int bid = blockIdx.x;
    const int lin = (bid & 7) * 64 + (bid >> 3);   // XCD swizzle
    const int b   = lin >> 8;
    const int t   = lin & 255;
    const int jstart = (t - WHALF) & ~3;           // fragment-aligned window base
    const int off8   = ((t - WHALF) - jstart) * 8; // 0/8/16/24
    const int fgbase = jstart >> 1;                // key0/16
    const int kcbase = jstart >> 2;                // key0/32
    const int tid = threadIdx.x;
    const int lane = tid & 63;
    const int h    = tid >> 6;

    // ---- key-valid mask over the aligned 288-key rectangle ----
    if (tid < 288) {
        const int j = jstart + (tid >> 3), m = tid & 7;
        const bool v = (j >= 0) && (j < TSEQ) && (j >= t - WHALF) && (j <= t + WHALF)
                       && (kpm[(b * TSEQ + j) * NAG + m] == 0);
        km[tid] = v ? 1 : 0;
    }

    // ---- QK^T per wave: D[8 real rows x 288], lane-linear K frags ----
    {
        const int n = lane & 7;
        const unsigned short* qbase = qb + ((size_t)(b * TSEQ + t) * NAG + n) * EE + h * HD;
        short8 aq0 = *(const short8*)(qbase + (lane >> 4) * 8);
        short8 aq1 = *(const short8*)(qbase + 32 + (lane >> 4) * 8);
        const unsigned short* kbase = kswz + (size_t)(b * 8 + h) * 131072;
        unsigned short* Ph = P16 + h * HS;
        const int r0 = (lane >> 4) * 4;
        const int cl = lane & 15;

        auto kfrag = [&](int f, int half) -> const short8* {
            int fg = fgbase + f;
            fg = (fg < 0) ? 0 : ((fg > 127) ? 127 : fg);
            return (const short8*)(kbase + fg * 1024 + half * 512 + lane * 8);
        };

        short8 ka0[4], ka1[4];
        #pragma unroll
        for (int f = 0; f < 4; ++f) { ka0[f] = *kfrag(f, 0); ka1[f] = *kfrag(f, 1); }
        #pragma unroll
        for (int f = 0; f < 18; ++f) {
            f32x4 a = (f32x4){0.f, 0.f, 0.f, 0.f};
            a = __builtin_amdgcn_mfma_f32_16x16x32_bf16(aq0, ka0[f & 3], a, 0, 0, 0);
            a = __builtin_amdgcn_mfma_f32_16x16x32_bf16(aq1, ka1[f & 3], a, 0, 0, 0);
            if (f + 4 < 18) { ka0[f & 3] = *kfrag(f + 4, 0); ka1[f & 3] = *kfrag(f + 4, 1); }
            if (r0 < 8) {
                #pragma unroll
                for (int rg = 0; rg < 4; ++rg)
                    Ph[(r0 + rg) * RSW + f * 16 + cl] = f2h(a[rg]);
            }
        }
    }
    __syncthreads();

    // ---- softmax per wave: 8 lanes/row; in-place f16 logits -> unnorm probs ----
    {
        const int r = lane & 7, sub = lane >> 3;
        unsigned short* prow = P16 + h * HS + r * RSW;
        float mx = -INFINITY;
        #pragma unroll
        for (int i = 0; i < 36; ++i) {
            const int c = sub + 8 * i;                 // < 288
            if (km[c]) mx = fmaxf(mx, h2f(prow[c]));
        }
        mx = fmaxf(mx, __shfl_xor(mx, 8));
        mx = fmaxf(mx, __shfl_xor(mx, 16));
        mx = fmaxf(mx, __shfl_xor(mx, 32));
        float sum = 0.f;
        #pragma unroll
        for (int i = 0; i < 36; ++i) {
            const int c = sub + 8 * i;
            float p = 0.f;
            if (km[c]) p = __expf(h2f(prow[c]) - mx);
            prow[c] = f2h(p);
            sum += p;
        }
        sum += __shfl_xor(sum, 8);
        sum += __shfl_xor(sum, 16);
        sum += __shfl_xor(sum, 32);
        if (sub == 0) invs[h * 8 + r] = 1.f / sum;
    }
    __syncthreads();

    // ---- PV V prefetch (lane-linear), issued before the attn store loop ----
    const unsigned short* vbase = vswz + (size_t)(b * 8 + h) * 131072;
    auto vfrag = [&](int ms, int df) -> const short8* {
        int kc = kcbase + ms;
        kc = (kc < 0) ? 0 : ((kc > 63) ? 63 : kc);
        return (const short8*)(vbase + kc * 2048 + df * 512 + lane * 8);
    };
    short8 vf[2][4];
    #pragma unroll
    for (int df = 0; df < 4; ++df) vf[0][df] = *vfrag(0, df);
    #pragma unroll
    for (int df = 0; df < 4; ++df) vf[1][df] = *vfrag(1, df);
    __builtin_amdgcn_sched_barrier(0);

    // ---- cooperative coalesced attn write: 4224 float4 contiguous ----
    {
        float* abase = attn + (size_t)(b * TSEQ + t) * (NAG * WN * NH);
        #pragma unroll 3
        for (int q4 = tid; q4 < 4224; q4 += 512) {
            const int hh = q4 & 1;
            const int rw = q4 >> 1;                    // n*264 + wm
            const int n  = rw / WN;
            const int wm = rw - n * WN;
            const int h0 = hh * 4;
            const unsigned short* pp = P16 + h0 * HS + n * RSW + wm + off8;
            float4 v;
            v.x = h2f(pp[0])      * invs[(h0 + 0) * 8 + n];
            v.y = h2f(pp[HS])     * invs[(h0 + 1) * 8 + n];
            v.z = h2f(pp[2 * HS]) * invs[(h0 + 2) * 8 + n];
            v.w = h2f(pp[3 * HS]) * invs[(h0 + 3) * 8 + n];
            *(float4*)(abase + (size_t)q4 * 4) = v;
        }
    }
    // no barrier: P16 is read-only from here on

    // ---- PV per wave: D[8 real rows x 64] f16 MFMA; inv applied to acc ----
    {
        const unsigned short* arow = P16 + h * HS + (lane & 7) * RSW;
        f32x4 acc[4];
        #pragma unroll
        for (int df = 0; df < 4; ++df) acc[df] = (f32x4){0.f, 0.f, 0.f, 0.f};

        #pragma unroll
        for (int ms = 0; ms < 9; ++ms) {
            short8 afr = *(const short8*)(arow + ms * 32 + (lane >> 4) * 8);
            #pragma unroll
            for (int df = 0; df < 4; ++df)
                acc[df] = __builtin_amdgcn_mfma_f32_16x16x32_f16(
                    as_f16x8(afr), as_f16x8(vf[ms & 1][df]), acc[df], 0, 0, 0);
            if (ms + 2 < 9) {
                #pragma unroll
                for (int df = 0; df < 4; ++df) vf[ms & 1][df] = *vfrag(ms + 2, df);
            }
        }
        const int r0 = (lane >> 4) * 4;
        if (r0 < 8) {
            float iv[4];
            #pragma unroll
            for (int rg = 0; rg < 4; ++rg) iv[rg] = invs[h * 8 + r0 + rg];
            #pragma unroll
            for (int df = 0; df < 4; ++df) {
                const int d = df * 16 + (lane & 15);
                #pragma unroll
                for (int rg = 0; rg < 4; ++rg) {
                    const int n = r0 + rg;
                    out[((size_t)(b * TSEQ + t) * NAG + n) * EE + h * HD + d] = acc[df][rg] * iv[rg];
                }
            }
        }
    }
}

extern "C" void kernel_launch(void* const* d_in, const int* in_sizes, int n_in,
                              void* d_out, int out_size, void* d_ws, size_t ws_size,
                              hipStream_t stream) {
    const float* query = (const float*)d_in[0];
    const float* key   = (const float*)d_in[1];
    const float* value = (const float*)d_in[2];
    const unsigned char* kpm = (const unsigned char*)d_in[3];
    const float* Wq = (const float*)d_in[4];
    const float* bq = (const float*)d_in[5];
    const float* Wk = (const float*)d_in[6];
    const float* bk = (const float*)d_in[7];
    const float* Wv = (const float*)d_in[8];
    const float* bv = (const float*)d_in[9];

    float* out  = (float*)d_out;
    float* attn = out + (size_t)NBATCH * TSEQ * NAG * EE;

    unsigned short* qbf  = (unsigned short*)d_ws;              // 4 MB bf16
    unsigned short* kswz = qbf + (size_t)4096 * EE;            // 4 MB bf16 frag-order K
    unsigned short* vswz = kswz + (size_t)4096 * EE;           // 4 MB f16 frag-order V

    dim3 gp(32, 4, 3);
    proj_mfma_kernel<<<gp, 256, 0, stream>>>(query, key, value,
                                             Wq, Wk, Wv, bq, bk, bv,
                                             qbf, kswz, vswz);

    (void)hipFuncSetAttribute((const void*)attn_fused_kernel,
                              hipFuncAttributeMaxDynamicSharedMemorySize, SMEM2_BYTES);
    attn_fused_kernel<<<512, 512, SMEM2_BYTES, stream>>>(qbf, kswz, vswz, kpm, out, attn);
}

// Round 14
// 44.768 us; speedup vs baseline: 1.6961x; 1.0148x over previous
//
#include <hip/hip_runtime.h>
#include <hip/hip_bf16.h>

#define TSEQ 256
#define NBATCH 2
#define NAG 8
#define NH 8
#define HD 64
#define EE 512
#define WHALF 16
#define WW 33
#define WN 264   // WW*NAG

typedef __attribute__((ext_vector_type(8))) short short8;
typedef __attribute__((ext_vector_type(4))) short short4v;
typedef __attribute__((ext_vector_type(4))) float f32x4;
typedef _Float16 f16x8 __attribute__((ext_vector_type(8)));

static __device__ __forceinline__ unsigned short f2bf(float f) {
    unsigned int u = __float_as_uint(f);
    unsigned int r = (u + 0x7FFFu + ((u >> 16) & 1u)) >> 16;
    return (unsigned short)r;
}
static __device__ __forceinline__ unsigned short f2h(float f) {
    _Float16 h = (_Float16)f;
    return __builtin_bit_cast(unsigned short, h);
}
static __device__ __forceinline__ float h2f(unsigned short u) {
    return (float)__builtin_bit_cast(_Float16, u);
}
static __device__ __forceinline__ f16x8 as_f16x8(short8 s) {
    return __builtin_bit_cast(f16x8, s);
}

// ---------------- fused QKV projection GEMM (bf16 MFMA) -----------------
// BM=128, BN=128, BK=64, 4 waves. z picks {q,k,v}.
// z==0: q normal bf16 [b,t,n,E].
// z==1: k in MFMA-fragment order (bf16), z==2: v in PV-fragment order (f16);
// both now staged through LDS so global stores are 16B-coalesced.
__global__ __launch_bounds__(256)
void proj_mfma_kernel(const float* __restrict__ xq, const float* __restrict__ xk,
                      const float* __restrict__ xv,
                      const float* __restrict__ Wq, const float* __restrict__ Wk,
                      const float* __restrict__ Wv,
                      const float* __restrict__ bq, const float* __restrict__ bk,
                      const float* __restrict__ bv,
                      unsigned short* __restrict__ oq,
                      unsigned short* __restrict__ kswz,
                      unsigned short* __restrict__ vswz)
{
    __shared__ __align__(16) char LS[32768];
    char* As = LS;             // 16 KB staging A
    char* Bs = LS + 16384;     // 16 KB staging B   (reused by epilogue repack)

    const float* x; const float* W; const float* bias; float scale;
    const int z = blockIdx.z;
    if (z == 0)      { x = xq; W = Wq; bias = bq; scale = 0.125f; }
    else if (z == 1) { x = xk; W = Wk; bias = bk; scale = 1.0f; }
    else             { x = xv; W = Wv; bias = bv; scale = 1.0f; }

    const int tid  = threadIdx.x;
    const int lane = tid & 63;
    const int wid  = tid >> 6;
    const int i0 = blockIdx.x * 128;
    const int f0 = blockIdx.y * 128;
    const int wr = wid >> 1, wc = wid & 1;

    f32x4 acc[4][4];
    #pragma unroll
    for (int m = 0; m < 4; ++m)
        #pragma unroll
        for (int n = 0; n < 4; ++n)
            acc[m][n] = (f32x4){0.f, 0.f, 0.f, 0.f};

    for (int k0 = 0; k0 < EE; k0 += 64) {
        #pragma unroll
        for (int it = 0; it < 8; ++it) {
            const int tt  = tid + it * 256;
            const int row = tt >> 4, f4 = tt & 15;
            float4 v4 = *reinterpret_cast<const float4*>(x + (size_t)(i0 + row) * EE + k0 + f4 * 4);
            short4v s;
            s[0] = (short)f2bf(v4.x); s[1] = (short)f2bf(v4.y);
            s[2] = (short)f2bf(v4.z); s[3] = (short)f2bf(v4.w);
            *(short4v*)(As + row * 128 + ((f4 * 8) ^ ((row & 7) << 4))) = s;
        }
        #pragma unroll
        for (int it = 0; it < 8; ++it) {
            const int tt  = tid + it * 256;
            const int row = tt >> 4, f4 = tt & 15;
            float4 v4 = *reinterpret_cast<const float4*>(W + (size_t)(f0 + row) * EE + k0 + f4 * 4);
            short4v s;
            s[0] = (short)f2bf(v4.x); s[1] = (short)f2bf(v4.y);
            s[2] = (short)f2bf(v4.z); s[3] = (short)f2bf(v4.w);
            *(short4v*)(Bs + row * 128 + ((f4 * 8) ^ ((row & 7) << 4))) = s;
        }
        __syncthreads();

        #pragma unroll
        for (int ks = 0; ks < 2; ++ks) {
            short8 a[4], b[4];
            #pragma unroll
            for (int m = 0; m < 4; ++m) {
                const int row = wr * 64 + m * 16 + (lane & 15);
                a[m] = *(short8*)(As + row * 128 +
                                  ((ks * 64 + (lane >> 4) * 16) ^ ((row & 7) << 4)));
            }
            #pragma unroll
            for (int n = 0; n < 4; ++n) {
                const int row = wc * 64 + n * 16 + (lane & 15);
                b[n] = *(short8*)(Bs + row * 128 +
                                  ((ks * 64 + (lane >> 4) * 16) ^ ((row & 7) << 4)));
            }
            #pragma unroll
            for (int m = 0; m < 4; ++m)
                #pragma unroll
                for (int n = 0; n < 4; ++n)
                    acc[m][n] = __builtin_amdgcn_mfma_f32_16x16x32_bf16(a[m], b[n], acc[m][n], 0, 0, 0);
        }
        __syncthreads();
    }

    if (z == 0) {
        #pragma unroll
        for (int n = 0; n < 4; ++n) {
            const int col = f0 + wc * 64 + n * 16 + (lane & 15);
            const float bb = bias[col];
            #pragma unroll
            for (int m = 0; m < 4; ++m)
                #pragma unroll
                for (int rg = 0; rg < 4; ++rg) {
                    const int row = i0 + wr * 64 + m * 16 + (lane >> 4) * 4 + rg;
                    oq[(size_t)row * EE + col] = f2bf((acc[m][n][rg] + bb) * scale);
                }
        }
    } else if (z == 1) {
        // ---- k: scatter to LDS in fragment order, then coalesced 16B stores ----
        unsigned short* ls16 = (unsigned short*)LS;
        const int b_ = i0 >> 11;
        const int c0 = i0 & 2047;
        const int h0 = f0 >> 6;
        #pragma unroll
        for (int n = 0; n < 4; ++n) {
            const int col = f0 + wc * 64 + n * 16 + (lane & 15);
            const int hl = (col >> 6) & 1;
            const int d  = col & 63;
            const float bb = bias[col];
            const int ib = (d >> 5) * 512 + ((d & 31) >> 3) * 128 + (d & 7);
            #pragma unroll
            for (int m = 0; m < 4; ++m) {
                #pragma unroll
                for (int rg = 0; rg < 4; ++rg) {
                    const int cl = wr * 64 + m * 16 + (lane >> 4) * 4 + rg;  // local key idx
                    ls16[(hl * 8 + (cl >> 4)) * 1024 + ib + (cl & 15) * 8] =
                        f2bf(acc[m][n][rg] + bb);
                }
            }
        }
        __syncthreads();
        #pragma unroll
        for (int it = 0; it < 8; ++it) {
            const int ci = tid + it * 256;             // 0..2047 16B-chunks
            const int hlfg = ci >> 7;
            const int hl = hlfg >> 3, fg = hlfg & 7;
            short8 v = *(short8*)(ls16 + ci * 8);
            *(short8*)(kswz + (size_t)(b_ * 8 + h0 + hl) * 131072 +
                       (size_t)((c0 >> 4) + fg) * 1024 + (ci & 127) * 8) = v;
        }
    } else {
        // ---- v: scatter to LDS in PV-fragment order, then coalesced stores ----
        unsigned short* ls16 = (unsigned short*)LS;
        const int b_ = i0 >> 11;
        const int c0 = i0 & 2047;
        const int h0 = f0 >> 6;
        #pragma unroll
        for (int n = 0; n < 4; ++n) {
            const int col = f0 + wc * 64 + n * 16 + (lane & 15);
            const int hl = (col >> 6) & 1;
            const int d  = col & 63;
            const float bb = bias[col];
            const int ib = (d >> 4) * 512 + (d & 15) * 8;
            #pragma unroll
            for (int m = 0; m < 4; ++m) {
                #pragma unroll
                for (int rg = 0; rg < 4; ++rg) {
                    const int cl = wr * 64 + m * 16 + (lane >> 4) * 4 + rg;
                    ls16[(hl * 4 + (cl >> 5)) * 2048 + ib + ((cl >> 3) & 3) * 128 + (cl & 7)] =
                        f2h(acc[m][n][rg] + bb);
                }
            }
        }
        __syncthreads();
        #pragma unroll
        for (int it = 0; it < 8; ++it) {
            const int ci = tid + it * 256;
            const int hlch = ci >> 8;
            const int hl = hlch >> 2, ch = hlch & 3;
            short8 v = *(short8*)(ls16 + ci * 8);
            *(short8*)(vswz + (size_t)(b_ * 8 + h0 + hl) * 131072 +
                       (size_t)((c0 >> 5) + ch) * 2048 + (ci & 255) * 8) = v;
        }
    }
}

// ---------------- fused all-heads windowed attention ------------------------
// Block = (b, t). 512 threads = 8 waves; wave w owns head h = w.
// K/V read via lane-linear fragment loads (1 KB contiguous per instruction).
// Window aligned: jstart = (t-16)&~3, 36 j's = 288 keys; off8 shifts attn cols.
#define RSW  296                        // u16 per P row
#define HS   2376                       // u16 per head buffer (8*296+8)
#define KM_OFF_B  (8 * HS * 2)          // 38016
#define INV_OFF_B (KM_OFF_B + 288)      // 38304
#define SMEM2_BYTES (INV_OFF_B + 256 + 32)

__global__ __launch_bounds__(512, 6)
void attn_fused_kernel(const unsigned short* __restrict__ qb,
                       const unsigned short* __restrict__ kswz,
                       const unsigned short* __restrict__ vswz,
                       const unsigned char* __restrict__ kpm,
                       float* __restrict__ out,
                       float* __restrict__ attn)
{
    extern __shared__ char smem[];
    unsigned short* P16 = (unsigned short*)smem;
    char*  km   = smem + KM_OFF_B;
    float* invs = (float*)(smem + INV_OFF_B);

    const int bid = blockIdx.x;
    const int lin = (bid & 7) * 64 + (bid >> 3);   // XCD swizzle
    const int b   = lin >> 8;
    const int t   = lin & 255;
    const int jstart = (t - WHALF) & ~3;           // fragment-aligned window base
    const int off8   = ((t - WHALF) - jstart) * 8; // 0/8/16/24
    const int fgbase = jstart >> 1;                // key0/16
    const int kcbase = jstart >> 2;                // key0/32
    const int tid = threadIdx.x;
    const int lane = tid & 63;
    const int h    = tid >> 6;

    // ---- key-valid mask over the aligned 288-key rectangle ----
    if (tid < 288) {
        const int j = jstart + (tid >> 3), m = tid & 7;
        const bool v = (j >= 0) && (j < TSEQ) && (j >= t - WHALF) && (j <= t + WHALF)
                       && (kpm[(b * TSEQ + j) * NAG + m] == 0);
        km[tid] = v ? 1 : 0;
    }

    // ---- QK^T per wave: D[8 real rows x 288], lane-linear K frags ----
    {
        const int n = lane & 7;
        const unsigned short* qbase = qb + ((size_t)(b * TSEQ + t) * NAG + n) * EE + h * HD;
        short8 aq0 = *(const short8*)(qbase + (lane >> 4) * 8);
        short8 aq1 = *(const short8*)(qbase + 32 + (lane >> 4) * 8);
        const unsigned short* kbase = kswz + (size_t)(b * 8 + h) * 131072;
        unsigned short* Ph = P16 + h * HS;
        const int r0 = (lane >> 4) * 4;
        const int cl = lane & 15;

        auto kfrag = [&](int f, int half) -> const short8* {
            int fg = fgbase + f;
            fg = (fg < 0) ? 0 : ((fg > 127) ? 127 : fg);
            return (const short8*)(kbase + fg * 1024 + half * 512 + lane * 8);
        };

        short8 ka0[4], ka1[4];
        #pragma unroll
        for (int f = 0; f < 4; ++f) { ka0[f] = *kfrag(f, 0); ka1[f] = *kfrag(f, 1); }
        #pragma unroll
        for (int f = 0; f < 18; ++f) {
            f32x4 a = (f32x4){0.f, 0.f, 0.f, 0.f};
            a = __builtin_amdgcn_mfma_f32_16x16x32_bf16(aq0, ka0[f & 3], a, 0, 0, 0);
            a = __builtin_amdgcn_mfma_f32_16x16x32_bf16(aq1, ka1[f & 3], a, 0, 0, 0);
            if (f + 4 < 18) { ka0[f & 3] = *kfrag(f + 4, 0); ka1[f & 3] = *kfrag(f + 4, 1); }
            if (r0 < 8) {
                #pragma unroll
                for (int rg = 0; rg < 4; ++rg)
                    Ph[(r0 + rg) * RSW + f * 16 + cl] = f2h(a[rg]);
            }
        }
    }
    __syncthreads();

    // ---- softmax per wave: 8 lanes/row; in-place f16 logits -> unnorm probs ----
    {
        const int r = lane & 7, sub = lane >> 3;
        unsigned short* prow = P16 + h * HS + r * RSW;
        float mx = -INFINITY;
        #pragma unroll
        for (int i = 0; i < 36; ++i) {
            const int c = sub + 8 * i;                 // < 288
            if (km[c]) mx = fmaxf(mx, h2f(prow[c]));
        }
        mx = fmaxf(mx, __shfl_xor(mx, 8));
        mx = fmaxf(mx, __shfl_xor(mx, 16));
        mx = fmaxf(mx, __shfl_xor(mx, 32));
        float sum = 0.f;
        #pragma unroll
        for (int i = 0; i < 36; ++i) {
            const int c = sub + 8 * i;
            float p = 0.f;
            if (km[c]) p = __expf(h2f(prow[c]) - mx);
            prow[c] = f2h(p);
            sum += p;
        }
        sum += __shfl_xor(sum, 8);
        sum += __shfl_xor(sum, 16);
        sum += __shfl_xor(sum, 32);
        if (sub == 0) invs[h * 8 + r] = 1.f / sum;
    }
    __syncthreads();

    // ---- PV V prefetch (lane-linear), issued before the attn store loop ----
    const unsigned short* vbase = vswz + (size_t)(b * 8 + h) * 131072;
    auto vfrag = [&](int ms, int df) -> const short8* {
        int kc = kcbase + ms;
        kc = (kc < 0) ? 0 : ((kc > 63) ? 63 : kc);
        return (const short8*)(vbase + kc * 2048 + df * 512 + lane * 8);
    };
    short8 vf[2][4];
    #pragma unroll
    for (int df = 0; df < 4; ++df) vf[0][df] = *vfrag(0, df);
    #pragma unroll
    for (int df = 0; df < 4; ++df) vf[1][df] = *vfrag(1, df);
    __builtin_amdgcn_sched_barrier(0);

    // ---- cooperative coalesced attn write: 4224 float4 contiguous ----
    {
        float* abase = attn + (size_t)(b * TSEQ + t) * (NAG * WN * NH);
        #pragma unroll 3
        for (int q4 = tid; q4 < 4224; q4 += 512) {
            const int hh = q4 & 1;
            const int rw = q4 >> 1;                    // n*264 + wm
            const int n  = rw / WN;
            const int wm = rw - n * WN;
            const int h0 = hh * 4;
            const unsigned short* pp = P16 + h0 * HS + n * RSW + wm + off8;
            float4 v;
            v.x = h2f(pp[0])      * invs[(h0 + 0) * 8 + n];
            v.y = h2f(pp[HS])     * invs[(h0 + 1) * 8 + n];
            v.z = h2f(pp[2 * HS]) * invs[(h0 + 2) * 8 + n];
            v.w = h2f(pp[3 * HS]) * invs[(h0 + 3) * 8 + n];
            *(float4*)(abase + (size_t)q4 * 4) = v;
        }
    }
    // no barrier: P16 is read-only from here on

    // ---- PV per wave: D[8 real rows x 64] f16 MFMA; inv applied to acc ----
    {
        const unsigned short* arow = P16 + h * HS + (lane & 7) * RSW;
        f32x4 acc[4];
        #pragma unroll
        for (int df = 0; df < 4; ++df) acc[df] = (f32x4){0.f, 0.f, 0.f, 0.f};

        #pragma unroll
        for (int ms = 0; ms < 9; ++ms) {
            short8 afr = *(const short8*)(arow + ms * 32 + (lane >> 4) * 8);
            #pragma unroll
            for (int df = 0; df < 4; ++df)
                acc[df] = __builtin_amdgcn_mfma_f32_16x16x32_f16(
                    as_f16x8(afr), as_f16x8(vf[ms & 1][df]), acc[df], 0, 0, 0);
            if (ms + 2 < 9) {
                #pragma unroll
                for (int df = 0; df < 4; ++df) vf[ms & 1][df] = *vfrag(ms + 2, df);
            }
        }
        const int r0 = (lane >> 4) * 4;
        if (r0 < 8) {
            float iv[4];
            #pragma unroll
            for (int rg = 0; rg < 4; ++rg) iv[rg] = invs[h * 8 + r0 + rg];
            #pragma unroll
            for (int df = 0; df < 4; ++df) {
                const int d = df * 16 + (lane & 15);
                #pragma unroll
                for (int rg = 0; rg < 4; ++rg) {
                    const int n = r0 + rg;
                    out[((size_t)(b * TSEQ + t) * NAG + n) * EE + h * HD + d] = acc[df][rg] * iv[rg];
                }
            }
        }
    }
}

extern "C" void kernel_launch(void* const* d_in, const int* in_sizes, int n_in,
                              void* d_out, int out_size, void* d_ws, size_t ws_size,
                              hipStream_t stream) {
    const float* query = (const float*)d_in[0];
    const float* key   = (const float*)d_in[1];
    const float* value = (const float*)d_in[2];
    const unsigned char* kpm = (const unsigned char*)d_in[3];
    const float* Wq = (const float*)d_in[4];
    const float* bq = (const float*)d_in[5];
    const float* Wk = (const float*)d_in[6];
    const float* bk = (const float*)d_in[7];
    const float* Wv = (const float*)d_in[8];
    const float* bv = (const float*)d_in[9];

    float* out  = (float*)d_out;
    float* attn = out + (size_t)NBATCH * TSEQ * NAG * EE;

    unsigned short* qbf  = (unsigned short*)d_ws;              // 4 MB bf16
    unsigned short* kswz = qbf + (size_t)4096 * EE;            // 4 MB bf16 frag-order K
    unsigned short* vswz = kswz + (size_t)4096 * EE;           // 4 MB f16 frag-order V

    dim3 gp(32, 4, 3);
    proj_mfma_kernel<<<gp, 256, 0, stream>>>(query, key, value,
                                             Wq, Wk, Wv, bq, bk, bv,
                                             qbf, kswz, vswz);

    (void)hipFuncSetAttribute((const void*)attn_fused_kernel,
                              hipFuncAttributeMaxDynamicSharedMemorySize, SMEM2_BYTES);
    attn_fused_kernel<<<512, 512, SMEM2_BYTES, stream>>>(qbf, kswz, vswz, kpm, out, attn);
}